// Round 4
// baseline (22.467 us; speedup 1.0000x reference)
//
#include <hip/hip_runtime.h>

#define CONF_THR 2.5f
#define NCLS 80
#define BLOCK 256
#define ITERS 2
#define ROWS_PER_BLOCK (64 * ITERS)   // 128 rows per block

// 4 lanes per row, 2 rows per thread. Pure load phase (12 loads in flight),
// then compute. VGPR budget kept <= 64 so 8 waves/SIMD fit (forced via
// __launch_bounds__ min-waves-per-EU arg).
__global__ __launch_bounds__(BLOCK, 8) void yolo_pass1(
    const float* __restrict__ post,
    const float* __restrict__ boxes,
    float* __restrict__ partial, int n) {

    const int tid  = threadIdx.x;
    const int lane = tid & 63;
    const int wav  = tid >> 6;
    const int q    = tid & 3;       // quarter-row / box-coord index
    const int sub  = tid >> 2;      // row-in-group 0..63
    const int base = blockIdx.x * ROWS_PER_BLOCK;

    float4 v[ITERS][5];
    float  bx[ITERS];

    // ---- load phase: all independent, all in flight ----
    #pragma unroll
    for (int it = 0; it < ITERS; ++it) {
        const int row = base + it * 64 + sub;
        if (row < n) {
            const float4* p = reinterpret_cast<const float4*>(
                post + (size_t)row * NCLS + q * 20);
            bx[it] = boxes[(size_t)row * 4 + q];
            v[it][0] = p[0]; v[it][1] = p[1]; v[it][2] = p[2];
            v[it][3] = p[3]; v[it][4] = p[4];
        } else {
            const float4 ninf = make_float4(-1e30f, -1e30f, -1e30f, -1e30f);
            v[it][0] = ninf; v[it][1] = ninf; v[it][2] = ninf;
            v[it][3] = ninf; v[it][4] = ninf;
            bx[it] = 0.0f;
        }
    }

    // ---- compute phase ----
    float c = 0.0f;
    #pragma unroll
    for (int it = 0; it < ITERS; ++it) {
        float m0 = fmaxf(fmaxf(v[it][0].x, v[it][0].y), fmaxf(v[it][0].z, v[it][0].w));
        float m1 = fmaxf(fmaxf(v[it][1].x, v[it][1].y), fmaxf(v[it][1].z, v[it][1].w));
        float m2 = fmaxf(fmaxf(v[it][2].x, v[it][2].y), fmaxf(v[it][2].z, v[it][2].w));
        float m3 = fmaxf(fmaxf(v[it][3].x, v[it][3].y), fmaxf(v[it][3].z, v[it][3].w));
        float m4 = fmaxf(fmaxf(v[it][4].x, v[it][4].y), fmaxf(v[it][4].z, v[it][4].w));
        float m  = fmaxf(fmaxf(fmaxf(m0, m1), fmaxf(m2, m3)), m4);
        // max across the 4-lane group sharing this row
        m = fmaxf(m, __shfl_xor(m, 1));
        m = fmaxf(m, __shfl_xor(m, 2));
        if (m >= CONF_THR) c += bx[it] + ((q == 0) ? m : 0.0f);
    }

    // 64-lane butterfly sum
    #pragma unroll
    for (int off = 1; off < 64; off <<= 1)
        c += __shfl_xor(c, off);

    __shared__ float ws[4];
    if (lane == 0) ws[wav] = c;
    __syncthreads();
    if (tid == 0) partial[blockIdx.x] = ws[0] + ws[1] + ws[2] + ws[3];
}

// Pass 2: reduce nb per-block partials -> scalar. Plain store, deterministic.
__global__ __launch_bounds__(1024) void yolo_pass2(
    const float* __restrict__ partial, float* __restrict__ out, int nb) {

    const int tid  = threadIdx.x;
    const int lane = tid & 63;
    const int wav  = tid >> 6;

    float s = 0.0f;
    for (int i = tid; i < nb; i += 1024) s += partial[i];

    #pragma unroll
    for (int off = 1; off < 64; off <<= 1)
        s += __shfl_xor(s, off);

    __shared__ float ws[16];
    if (lane == 0) ws[wav] = s;
    __syncthreads();
    if (tid == 0) {
        float t = 0.0f;
        #pragma unroll
        for (int w = 0; w < 16; ++w) t += ws[w];
        out[0] = t;
    }
}

extern "C" void kernel_launch(void* const* d_in, const int* in_sizes, int n_in,
                              void* d_out, int out_size, void* d_ws, size_t ws_size,
                              hipStream_t stream) {
    const float* post  = (const float*)d_in[0];   // [N, 80] f32
    const float* boxes = (const float*)d_in[1];   // [N, 4]  f32
    float* out     = (float*)d_out;               // scalar f32
    float* partial = (float*)d_ws;                // nb floats of scratch

    const int n  = in_sizes[0] / NCLS;            // 300000
    const int nb = (n + ROWS_PER_BLOCK - 1) / ROWS_PER_BLOCK;   // 2344

    yolo_pass1<<<nb, BLOCK, 0, stream>>>(post, boxes, partial, n);
    yolo_pass2<<<1, 1024, 0, stream>>>(partial, out, nb);
}